// Round 2
// 290.233 us; speedup vs baseline: 1.0289x; 1.0289x over previous
//
#include <hip/hip_runtime.h>
#include <math.h>

#define NB 8
#define NC 256
#define HS 64
#define WSM 64
#define HL 512
#define WL 512
#define NK 21
#define PS (HS*WSM)     /* 4096 */
#define PL (HL*WL)      /* 262144 */

#define NROWS (NB*3*HL)             /* 12288 adj_x rows */
#define WT_ELEMS (NK*NC)            /* 5376 */
#define WT_BLOCKS ((WT_ELEMS+63)/64) /* 84 */

typedef float fx4 __attribute__((ext_vector_type(4)));

// ws layout (floats):
//   Wt:  [256][32]  (c-major, padded)   off 0       size 8192
//   T1:  [B,3,HL,WSM]                   off 8192    size 786432
//   A:   [B,3,PS]                       off 794624  size 98304
//   q:   [B,K,3]                        off 892928  size 504

// fused prep: adj_x rows + W transpose + q zero-init (independent jobs by blockIdx)
__global__ __launch_bounds__(64) void k_prep(
    const float* __restrict__ x, const float* __restrict__ Wc,
    float* __restrict__ T1, float* __restrict__ Wt, float* __restrict__ q)
{
    int blk = blockIdx.x;
    int tid = threadIdx.x;

    if (blk < NROWS) {
        // horizontal adjoint: T1[row, w] = sum_X wgt(w<-X) * x[row, X]
        __shared__ float row[WL];
        const fx4* src4 = (const fx4*)(x + (size_t)blk * WL);
        fx4* row4 = (fx4*)row;
        row4[tid]      = src4[tid];        // 512 floats = 128 fx4 = 64 lanes x 2
        row4[tid + 64] = src4[tid + 64];
        __syncthreads();

        const int w = tid;
        const float scale = 63.0f / 511.0f;
        const float inv_scale = 511.0f / 63.0f;
        int Xlo = max(0,    (int)floorf((w - 1) * inv_scale) - 1);
        int Xhi = min(WL-1, (int)ceilf ((w + 1) * inv_scale) + 1);
        float acc = 0.f;
        for (int X = Xlo; X <= Xhi; ++X) {
            float fs = X * scale;
            int i0 = (int)fs; if (i0 > WSM-1) i0 = WSM-1;
            float f = fs - (float)i0;
            int i1 = min(i0 + 1, WSM-1);
            float wt = (i0 == w ? 1.f - f : 0.f) + (i1 == w ? f : 0.f);
            acc += wt * row[X];
        }
        T1[(size_t)blk * WSM + w] = acc;
    } else if (blk < NROWS + WT_BLOCKS) {
        // transpose W_cls [21,256] -> Wt [256,32] (c-major, padded stride 32)
        int i = (blk - NROWS) * 64 + tid;
        if (i < WT_ELEMS) {
            int c = i / NK;
            int k = i - c*NK;
            Wt[c*32 + k] = Wc[k*NC + c];
        }
    } else {
        for (int i = tid; i < NB*NK*3; i += 64) q[i] = 0.f;
    }
}

// vertical adjoint: A[b,c,h,w] = sum_Y wgt(h<-Y) * T1[b,c,Y,w]
__global__ __launch_bounds__(256) void k_adj_y(
    const float* __restrict__ T1, float* __restrict__ A)
{
    int g = blockIdx.x * 256 + threadIdx.x;   // B*3*PS = 98304
    int w = g & (WSM-1);
    int h = (g >> 6) & (HS-1);
    int bcid = g >> 12;                        // 0..23
    const float scale = 63.0f / 511.0f;
    const float inv_scale = 511.0f / 63.0f;
    int Ylo = max(0,    (int)floorf((h - 1) * inv_scale) - 1);
    int Yhi = min(HL-1, (int)ceilf ((h + 1) * inv_scale) + 1);
    const float* src = T1 + (size_t)bcid * HL * WSM + w;
    float acc = 0.f;
    for (int Y = Ylo; Y <= Yhi; ++Y) {
        float fs = Y * scale;
        int i0 = (int)fs; if (i0 > HS-1) i0 = HS-1;
        float f = fs - (float)i0;
        int i1 = min(i0 + 1, HS-1);
        float wt = (i0 == h ? 1.f - f : 0.f) + (i1 == h ? f : 0.f);
        acc += wt * src[(size_t)Y * WSM];
    }
    A[g] = acc;
}

// fused: logits (W via uniform s_loads) + softmax + q-reduction.
// 4 waves per block split the c-loop 4-way (64 c each), combine partial logits
// through LDS, then split the k-loop of the q-reduce across waves.
// q[b,k,c] += sum over this block's 64 pixels of seg[k]*A[c]; scaled by 1/PL in k_out.
__global__ __launch_bounds__(256) void k_fused(
    const float* __restrict__ fm, const float* __restrict__ Wt,
    const float* __restrict__ bc, const float* __restrict__ A,
    float* __restrict__ q)
{
    int b = blockIdx.y;
    int lane = threadIdx.x & 63;
    int wv   = threadIdx.x >> 6;              // 0..3: c-slice owner
    int p = blockIdx.x * 64 + lane;

    float part[NK];
    #pragma unroll
    for (int k = 0; k < NK; ++k) part[k] = 0.f;

    const float* fmb = fm + (size_t)b * NC * PS + (size_t)(wv * 64) * PS + p;
    #pragma unroll 8
    for (int cc = 0; cc < 64; ++cc) {
        float v = __builtin_nontemporal_load(fmb + (size_t)cc * PS);
        const float* w = Wt + (wv * 64 + cc) * 32;   // uniform address -> s_load
        #pragma unroll
        for (int k = 0; k < NK; ++k) part[k] = fmaf(v, w[k], part[k]);
    }

    __shared__ float red[4][NK][64];          // 21.5 KB
    #pragma unroll
    for (int k = 0; k < NK; ++k) red[wv][k][lane] = part[k];
    __syncthreads();

    // every wave reconstructs the full logits (redundant but parallel-free)
    float logit[NK];
    #pragma unroll
    for (int k = 0; k < NK; ++k)
        logit[k] = bc[k] + ((red[0][k][lane] + red[1][k][lane])
                          + (red[2][k][lane] + red[3][k][lane]));

    float m = logit[0];
    #pragma unroll
    for (int k = 1; k < NK; ++k) m = fmaxf(m, logit[k]);
    float s = 0.f;
    #pragma unroll
    for (int k = 0; k < NK; ++k) { logit[k] = __expf(logit[k] - m); s += logit[k]; }
    float inv = 1.f / s;

    const float* Ab = A + (size_t)b * 3 * PS + p;
    float a0 = Ab[0], a1 = Ab[PS], a2 = Ab[2*PS];

    float* qb = q + b * NK * 3;
    for (int k = wv; k < NK; k += 4) {        // k-split across the 4 waves
        float sv = logit[k] * inv;
        float r0 = sv * a0, r1 = sv * a1, r2 = sv * a2;
        #pragma unroll
        for (int off = 32; off; off >>= 1) {
            r0 += __shfl_down(r0, off);
            r1 += __shfl_down(r1, off);
            r2 += __shfl_down(r2, off);
        }
        if (lane == 0) {
            atomicAdd(qb + k*3 + 0, r0);
            atomicAdd(qb + k*3 + 1, r1);
            atomicAdd(qb + k*3 + 2, r2);
        }
    }
}

// out[b,k,p] = sum_c x[b,c,p] * q[b,k,c]/PL   (fx4 over p, nontemporal stores)
__global__ __launch_bounds__(256) void k_out(
    const float* __restrict__ x, const float* __restrict__ q,
    float* __restrict__ out)
{
    __shared__ float sq[NK*3];
    int tid = threadIdx.x;
    int b = blockIdx.y;
    if (tid < NK*3) sq[tid] = q[b*NK*3 + tid] * (1.0f / (float)PL);
    __syncthreads();

    int p4 = blockIdx.x * 256 + tid;          // 65536 fx4 per image
    const fx4* xb = (const fx4*)(x + (size_t)b * 3 * PL);
    fx4 x0 = xb[p4];
    fx4 x1 = xb[PL/4 + p4];
    fx4 x2 = xb[2*(PL/4) + p4];
    fx4* ob = (fx4*)(out + (size_t)b * NK * PL);
    #pragma unroll
    for (int k = 0; k < NK; ++k) {
        fx4 o = sq[k*3+0]*x0 + sq[k*3+1]*x1 + sq[k*3+2]*x2;
        __builtin_nontemporal_store(o, ob + (size_t)k * (PL/4) + p4);
    }
}

extern "C" void kernel_launch(void* const* d_in, const int* in_sizes, int n_in,
                              void* d_out, int out_size, void* d_ws, size_t ws_size,
                              hipStream_t stream)
{
    const float* fm = (const float*)d_in[0];   // [8,256,64,64]
    const float* x  = (const float*)d_in[1];   // [8,3,512,512]
    const float* Wc = (const float*)d_in[2];   // [21,256]
    const float* bc = (const float*)d_in[3];   // [21]
    float* out = (float*)d_out;                // [8,21,512,512]

    float* ws = (float*)d_ws;
    float* Wt = ws;                   // 8192
    float* T1 = Wt + 8192;            // 786432
    float* A  = T1 + 786432;          // 98304
    float* q  = A + 98304;            // 504

    k_prep<<<NROWS + WT_BLOCKS + 1, 64, 0, stream>>>(x, Wc, T1, Wt, q);
    k_adj_y<<<NB*3*PS/256, 256, 0, stream>>>(T1, A);
    k_fused<<<dim3(PS/64, NB), 256, 0, stream>>>(fm, Wt, bc, A, q);
    k_out<<<dim3(PL/4/256, NB), 256, 0, stream>>>(x, q, out);
}

// Round 3
// 279.926 us; speedup vs baseline: 1.0668x; 1.0368x over previous
//
#include <hip/hip_runtime.h>
#include <math.h>

#define NB 8
#define NC 256
#define HS 64
#define WSM 64
#define HL 512
#define WL 512
#define NK 21
#define PS (HS*WSM)     /* 4096 */
#define PL (HL*WL)      /* 262144 */

#define NROWS (NB*3*HL)             /* 12288 adj_x rows */
#define WT_ELEMS (NK*NC)            /* 5376 */
#define WT_BLOCKS ((WT_ELEMS+63)/64) /* 84 */

typedef float fx4 __attribute__((ext_vector_type(4)));

// ws layout (floats):
//   Wt:  [256][32]  (c-major, padded)   off 0       size 8192
//   T1:  [B,3,HL,WSM]                   off 8192    size 786432
//   q:   [B,K,3]                        off 794624  size 504

// fused prep: adj_x rows + W transpose + q zero-init (independent jobs by blockIdx)
__global__ __launch_bounds__(64) void k_prep(
    const float* __restrict__ x, const float* __restrict__ Wc,
    float* __restrict__ T1, float* __restrict__ Wt, float* __restrict__ q)
{
    int blk = blockIdx.x;
    int tid = threadIdx.x;

    if (blk < NROWS) {
        // horizontal adjoint: T1[row, w] = sum_X wgt(w<-X) * x[row, X]
        __shared__ float row[WL];
        const fx4* src4 = (const fx4*)(x + (size_t)blk * WL);
        fx4* row4 = (fx4*)row;
        row4[tid]      = src4[tid];        // 512 floats = 128 fx4 = 64 lanes x 2
        row4[tid + 64] = src4[tid + 64];
        __syncthreads();

        const int w = tid;
        const float scale = 63.0f / 511.0f;
        const float inv_scale = 511.0f / 63.0f;
        int Xlo = max(0,    (int)floorf((w - 1) * inv_scale) - 1);
        int Xhi = min(WL-1, (int)ceilf ((w + 1) * inv_scale) + 1);
        float acc = 0.f;
        for (int X = Xlo; X <= Xhi; ++X) {
            float fs = X * scale;
            int i0 = (int)fs; if (i0 > WSM-1) i0 = WSM-1;
            float f = fs - (float)i0;
            int i1 = min(i0 + 1, WSM-1);
            float wt = (i0 == w ? 1.f - f : 0.f) + (i1 == w ? f : 0.f);
            acc += wt * row[X];
        }
        T1[(size_t)blk * WSM + w] = acc;
    } else if (blk < NROWS + WT_BLOCKS) {
        // transpose W_cls [21,256] -> Wt [256,32] (c-major, padded stride 32)
        int i = (blk - NROWS) * 64 + tid;
        if (i < WT_ELEMS) {
            int c = i / NK;
            int k = i - c*NK;
            Wt[c*32 + k] = Wc[k*NC + c];
        }
    } else {
        for (int i = tid; i < NB*NK*3; i += 64) q[i] = 0.f;
    }
}

// fused: vertical adjoint (A-row from T1, waves 0-2 -> LDS) + logits
// (4-wave c-split, W via uniform s_loads) + softmax + q-reduction.
// blockIdx.x = h (small-grid row); this block's 64 pixels are p = h*64 + w.
// q[b,k,c] += sum over this block's 64 pixels of seg[k]*A[c]; scaled by 1/PL in k_out.
__global__ __launch_bounds__(256) void k_fused(
    const float* __restrict__ fm, const float* __restrict__ Wt,
    const float* __restrict__ bc, const float* __restrict__ T1,
    float* __restrict__ q)
{
    int b = blockIdx.y;
    int lane = threadIdx.x & 63;
    int wv   = threadIdx.x >> 6;              // 0..3: c-slice owner
    int h    = blockIdx.x;                    // 0..63
    int p = h * 64 + lane;

    __shared__ float sA[3][64];
    __shared__ float red[4][NK][64];          // 21.5 KB

    // waves 0..2: vertical adjoint for channel wv at row h (18 coalesced L2 loads)
    if (wv < 3) {
        const float scale = 63.0f / 511.0f;
        const float inv_scale = 511.0f / 63.0f;
        int Ylo = max(0,    (int)floorf((h - 1) * inv_scale) - 1);
        int Yhi = min(HL-1, (int)ceilf ((h + 1) * inv_scale) + 1);
        const float* src = T1 + (size_t)(b*3 + wv) * HL * WSM + lane;
        float acc = 0.f;
        for (int Y = Ylo; Y <= Yhi; ++Y) {
            float fs = Y * scale;
            int i0 = (int)fs; if (i0 > HS-1) i0 = HS-1;
            float f = fs - (float)i0;
            int i1 = min(i0 + 1, HS-1);
            float wt = (i0 == h ? 1.f - f : 0.f) + (i1 == h ? f : 0.f);
            acc += wt * src[(size_t)Y * WSM];
        }
        sA[wv][lane] = acc;
    }

    float part[NK];
    #pragma unroll
    for (int k = 0; k < NK; ++k) part[k] = 0.f;

    const float* fmb = fm + (size_t)b * NC * PS + (size_t)(wv * 64) * PS + p;
    #pragma unroll 8
    for (int cc = 0; cc < 64; ++cc) {
        float v = __builtin_nontemporal_load(fmb + (size_t)cc * PS);
        const float* w = Wt + (wv * 64 + cc) * 32;   // uniform address -> s_load
        #pragma unroll
        for (int k = 0; k < NK; ++k) part[k] = fmaf(v, w[k], part[k]);
    }

    #pragma unroll
    for (int k = 0; k < NK; ++k) red[wv][k][lane] = part[k];
    __syncthreads();

    // every wave reconstructs the full logits (redundant but parallel-free)
    float logit[NK];
    #pragma unroll
    for (int k = 0; k < NK; ++k)
        logit[k] = bc[k] + ((red[0][k][lane] + red[1][k][lane])
                          + (red[2][k][lane] + red[3][k][lane]));

    float m = logit[0];
    #pragma unroll
    for (int k = 1; k < NK; ++k) m = fmaxf(m, logit[k]);
    float s = 0.f;
    #pragma unroll
    for (int k = 0; k < NK; ++k) { logit[k] = __expf(logit[k] - m); s += logit[k]; }
    float inv = 1.f / s;

    float a0 = sA[0][lane], a1 = sA[1][lane], a2 = sA[2][lane];

    float* qb = q + b * NK * 3;
    for (int k = wv; k < NK; k += 4) {        // k-split across the 4 waves
        float sv = logit[k] * inv;
        float r0 = sv * a0, r1 = sv * a1, r2 = sv * a2;
        #pragma unroll
        for (int off = 32; off; off >>= 1) {
            r0 += __shfl_down(r0, off);
            r1 += __shfl_down(r1, off);
            r2 += __shfl_down(r2, off);
        }
        if (lane == 0) {
            atomicAdd(qb + k*3 + 0, r0);
            atomicAdd(qb + k*3 + 1, r1);
            atomicAdd(qb + k*3 + 2, r2);
        }
    }
}

// out[b,k,p] = sum_c x[b,c,p] * q[b,k,c]/PL   (fx4 over p, nontemporal stores)
__global__ __launch_bounds__(256) void k_out(
    const float* __restrict__ x, const float* __restrict__ q,
    float* __restrict__ out)
{
    __shared__ float sq[NK*3];
    int tid = threadIdx.x;
    int b = blockIdx.y;
    if (tid < NK*3) sq[tid] = q[b*NK*3 + tid] * (1.0f / (float)PL);
    __syncthreads();

    int p4 = blockIdx.x * 256 + tid;          // 65536 fx4 per image
    const fx4* xb = (const fx4*)(x + (size_t)b * 3 * PL);
    fx4 x0 = xb[p4];
    fx4 x1 = xb[PL/4 + p4];
    fx4 x2 = xb[2*(PL/4) + p4];
    fx4* ob = (fx4*)(out + (size_t)b * NK * PL);
    #pragma unroll
    for (int k = 0; k < NK; ++k) {
        fx4 o = sq[k*3+0]*x0 + sq[k*3+1]*x1 + sq[k*3+2]*x2;
        __builtin_nontemporal_store(o, ob + (size_t)k * (PL/4) + p4);
    }
}

extern "C" void kernel_launch(void* const* d_in, const int* in_sizes, int n_in,
                              void* d_out, int out_size, void* d_ws, size_t ws_size,
                              hipStream_t stream)
{
    const float* fm = (const float*)d_in[0];   // [8,256,64,64]
    const float* x  = (const float*)d_in[1];   // [8,3,512,512]
    const float* Wc = (const float*)d_in[2];   // [21,256]
    const float* bc = (const float*)d_in[3];   // [21]
    float* out = (float*)d_out;                // [8,21,512,512]

    float* ws = (float*)d_ws;
    float* Wt = ws;                   // 8192
    float* T1 = Wt + 8192;            // 786432
    float* q  = T1 + 786432;          // 504

    k_prep<<<NROWS + WT_BLOCKS + 1, 64, 0, stream>>>(x, Wc, T1, Wt, q);
    k_fused<<<dim3(HS, NB), 256, 0, stream>>>(fm, Wt, bc, T1, q);
    k_out<<<dim3(PL/4/256, NB), 256, 0, stream>>>(x, q, out);
}

// Round 4
// 268.769 us; speedup vs baseline: 1.1111x; 1.0415x over previous
//
#include <hip/hip_runtime.h>
#include <math.h>

#define NB 8
#define NC 256
#define HS 64
#define WSM 64
#define HL 512
#define WL 512
#define NK 21
#define PS (HS*WSM)     /* 4096 */
#define PL (HL*WL)      /* 262144 */

#define WT_ELEMS (NK*NC)            /* 5376 */
#define WT_BLOCKS ((WT_ELEMS+63)/64) /* 84 */

typedef float fx4 __attribute__((ext_vector_type(4)));

// ws layout (floats):
//   Wt:  [256][32]  (c-major, padded)   off 0     size 8192
//   q:   [B,K,3]                        off 8192  size 504

// mini prep: W transpose + q zero-init only (85 tiny blocks)
__global__ __launch_bounds__(64) void k_prep(
    const float* __restrict__ Wc, float* __restrict__ Wt, float* __restrict__ q)
{
    int blk = blockIdx.x;
    int tid = threadIdx.x;
    if (blk < WT_BLOCKS) {
        int i = blk * 64 + tid;
        if (i < WT_ELEMS) {
            int c = i / NK;
            int k = i - c*NK;
            Wt[c*32 + k] = Wc[k*NC + c];
        }
    } else {
        for (int i = tid; i < NB*NK*3; i += 64) q[i] = 0.f;
    }
}

// fused: full separable bilinear adjoint from x (waves 0-2: vertical 18-tap
// into LDS tmp, then horizontal 18-tap -> sA) + logits (4-wave c-split,
// W via uniform s_loads) + softmax + q-reduction.
// XCD swizzle: swz=(id&7)*64+id/8 -> XCD k processes image b=k only, so its
// 3 MB x-slice stays resident in that XCD's 4 MB L2 across the ~2.2x re-read.
__global__ __launch_bounds__(256) void k_fused(
    const float* __restrict__ fm, const float* __restrict__ Wt,
    const float* __restrict__ bc, const float* __restrict__ x,
    float* __restrict__ q)
{
    int id = blockIdx.x;                      // 0..511
    int swz = (id & 7) * 64 + (id >> 3);
    int b = swz >> 6;
    int h = swz & 63;
    int lane = threadIdx.x & 63;
    int wv   = threadIdx.x >> 6;              // 0..3: c-slice owner
    int p = h * 64 + lane;

    __shared__ float tmp[3][WL];              // 6 KB vertical-pass scratch
    __shared__ float sA[3][64];
    __shared__ float red[4][NK][64];          // 21.5 KB

    const float scale = 63.0f / 511.0f;
    const float inv_scale = 511.0f / 63.0f;

    // waves 0..2: adjoint for channel wv at small-row h
    if (wv < 3) {
        // vertical: tmp[wv][X] = sum_Y wy(h,Y) * x[b,wv,Y,X]
        int Ylo = max(0,    (int)floorf((h - 1) * inv_scale) - 1);
        int Yhi = min(HL-1, (int)ceilf ((h + 1) * inv_scale) + 1);
        const float* xc = x + (size_t)(b*3 + wv) * PL;
        fx4 acc0 = {0.f,0.f,0.f,0.f}, acc1 = {0.f,0.f,0.f,0.f};
        for (int Y = Ylo; Y <= Yhi; ++Y) {
            float fs = Y * scale;
            int i0 = (int)fs; if (i0 > HS-1) i0 = HS-1;
            float f = fs - (float)i0;
            int i1 = min(i0 + 1, HS-1);
            float wt = (i0 == h ? 1.f - f : 0.f) + (i1 == h ? f : 0.f);
            const fx4* xr = (const fx4*)(xc + (size_t)Y * WL);
            acc0 += wt * xr[lane];
            acc1 += wt * xr[lane + 64];
        }
        fx4* t4 = (fx4*)tmp[wv];
        t4[lane]      = acc0;
        t4[lane + 64] = acc1;
        // horizontal (same wave -> lgkmcnt ordering, no barrier needed):
        // sA[wv][w] = sum_X wx(w,X) * tmp[wv][X]
        const int w_ = lane;
        int Xlo = max(0,    (int)floorf((w_ - 1) * inv_scale) - 1);
        int Xhi = min(WL-1, (int)ceilf ((w_ + 1) * inv_scale) + 1);
        float a = 0.f;
        for (int X = Xlo; X <= Xhi; ++X) {
            float fs = X * scale;
            int i0 = (int)fs; if (i0 > WSM-1) i0 = WSM-1;
            float f = fs - (float)i0;
            int i1 = min(i0 + 1, WSM-1);
            float wt = (i0 == w_ ? 1.f - f : 0.f) + (i1 == w_ ? f : 0.f);
            a = fmaf(wt, tmp[wv][X], a);
        }
        sA[wv][lane] = a;
    }

    // all 4 waves: logits partial over this wave's 64-channel slice
    float part[NK];
    #pragma unroll
    for (int k = 0; k < NK; ++k) part[k] = 0.f;

    const float* fmb = fm + (size_t)b * NC * PS + (size_t)(wv * 64) * PS + p;
    #pragma unroll 8
    for (int cc = 0; cc < 64; ++cc) {
        float v = __builtin_nontemporal_load(fmb + (size_t)cc * PS);
        const float* w = Wt + (wv * 64 + cc) * 32;   // uniform address -> s_load
        #pragma unroll
        for (int k = 0; k < NK; ++k) part[k] = fmaf(v, w[k], part[k]);
    }

    #pragma unroll
    for (int k = 0; k < NK; ++k) red[wv][k][lane] = part[k];
    __syncthreads();

    // every wave reconstructs the full logits (redundant but parallel-free)
    float logit[NK];
    #pragma unroll
    for (int k = 0; k < NK; ++k)
        logit[k] = bc[k] + ((red[0][k][lane] + red[1][k][lane])
                          + (red[2][k][lane] + red[3][k][lane]));

    float m = logit[0];
    #pragma unroll
    for (int k = 1; k < NK; ++k) m = fmaxf(m, logit[k]);
    float s = 0.f;
    #pragma unroll
    for (int k = 0; k < NK; ++k) { logit[k] = __expf(logit[k] - m); s += logit[k]; }
    float inv = 1.f / s;

    float a0 = sA[0][lane], a1 = sA[1][lane], a2 = sA[2][lane];

    float* qb = q + b * NK * 3;
    for (int k = wv; k < NK; k += 4) {        // k-split across the 4 waves
        float sv = logit[k] * inv;
        float r0 = sv * a0, r1 = sv * a1, r2 = sv * a2;
        #pragma unroll
        for (int off = 32; off; off >>= 1) {
            r0 += __shfl_down(r0, off);
            r1 += __shfl_down(r1, off);
            r2 += __shfl_down(r2, off);
        }
        if (lane == 0) {
            atomicAdd(qb + k*3 + 0, r0);
            atomicAdd(qb + k*3 + 1, r1);
            atomicAdd(qb + k*3 + 2, r2);
        }
    }
}

// out[b,k,p] = sum_c x[b,c,p] * q[b,k,c]/PL   (fx4 over p, nontemporal stores)
__global__ __launch_bounds__(256) void k_out(
    const float* __restrict__ x, const float* __restrict__ q,
    float* __restrict__ out)
{
    __shared__ float sq[NK*3];
    int tid = threadIdx.x;
    int b = blockIdx.y;
    if (tid < NK*3) sq[tid] = q[b*NK*3 + tid] * (1.0f / (float)PL);
    __syncthreads();

    int p4 = blockIdx.x * 256 + tid;          // 65536 fx4 per image
    const fx4* xb = (const fx4*)(x + (size_t)b * 3 * PL);
    fx4 x0 = xb[p4];
    fx4 x1 = xb[PL/4 + p4];
    fx4 x2 = xb[2*(PL/4) + p4];
    fx4* ob = (fx4*)(out + (size_t)b * NK * PL);
    #pragma unroll
    for (int k = 0; k < NK; ++k) {
        fx4 o = sq[k*3+0]*x0 + sq[k*3+1]*x1 + sq[k*3+2]*x2;
        __builtin_nontemporal_store(o, ob + (size_t)k * (PL/4) + p4);
    }
}

extern "C" void kernel_launch(void* const* d_in, const int* in_sizes, int n_in,
                              void* d_out, int out_size, void* d_ws, size_t ws_size,
                              hipStream_t stream)
{
    const float* fm = (const float*)d_in[0];   // [8,256,64,64]
    const float* x  = (const float*)d_in[1];   // [8,3,512,512]
    const float* Wc = (const float*)d_in[2];   // [21,256]
    const float* bc = (const float*)d_in[3];   // [21]
    float* out = (float*)d_out;                // [8,21,512,512]

    float* ws = (float*)d_ws;
    float* Wt = ws;                   // 8192
    float* q  = Wt + 8192;            // 504

    k_prep<<<WT_BLOCKS + 1, 64, 0, stream>>>(Wc, Wt, q);
    k_fused<<<NB*HS, 256, 0, stream>>>(fm, Wt, bc, x, q);
    k_out<<<dim3(PL/4/256, NB), 256, 0, stream>>>(x, q, out);
}

// Round 5
// 237.626 us; speedup vs baseline: 1.2567x; 1.1311x over previous
//
#include <hip/hip_runtime.h>
#include <math.h>

#define NB 8
#define NC 256
#define HS 64
#define WSM 64
#define HL 512
#define WL 512
#define NK 21
#define PS (HS*WSM)     /* 4096 */
#define PL (HL*WL)      /* 262144 */

#define WT_ELEMS (NK*NC)            /* 5376 */

typedef float fx4 __attribute__((ext_vector_type(4)));

// ws layout (floats):
//   qpart: [B*64][64]  (per-block q partials, padded)  off 0  size 32768
// No prep kernel: W staged per-block in LDS; qpart slots each written
// exactly once (no atomics -> no zero-init dependency).

// fused: W-transpose staging (all waves -> LDS) + separable bilinear adjoint
// from x (waves 0-2: vertical 18-tap into LDS tmp, then horizontal 18-tap ->
// sA) + logits (4-wave c-split, W via LDS broadcast) + softmax + q-partials.
// XCD swizzle: swz=(id&7)*64+id/8 -> XCD k processes image b=k only, so its
// 3 MB x-slice stays resident in that XCD's 4 MB L2 across the ~2.2x re-read.
__global__ __launch_bounds__(256) void k_fused(
    const float* __restrict__ fm, const float* __restrict__ Wc,
    const float* __restrict__ bc, const float* __restrict__ x,
    float* __restrict__ qpart)
{
    int id = blockIdx.x;                      // 0..511
    int swz = (id & 7) * 64 + (id >> 3);
    int b = swz >> 6;
    int h = swz & 63;
    int lane = threadIdx.x & 63;
    int wv   = threadIdx.x >> 6;              // 0..3: c-slice owner
    int p = h * 64 + lane;

    __shared__ float sWt[NC*22];              // 22 KB transposed W, stride 22
    __shared__ float tmp[3][WL];              // 6 KB vertical-pass scratch
    __shared__ float sA[3][64];
    __shared__ float red[4][NK][64];          // 21.5 KB

    // all waves: stage W transposed (coalesced global read, 2-way LDS alias)
    for (int i = threadIdx.x; i < WT_ELEMS; i += 256) {
        int k = i >> 8;                       // Wc is [k][c] row-major
        int c = i & 255;
        sWt[c*22 + k] = Wc[i];
    }

    const float scale = 63.0f / 511.0f;
    const float inv_scale = 511.0f / 63.0f;

    // waves 0..2: adjoint for channel wv at small-row h
    if (wv < 3) {
        // vertical: tmp[wv][X] = sum_Y wy(h,Y) * x[b,wv,Y,X]
        int Ylo = max(0,    (int)floorf((h - 1) * inv_scale) - 1);
        int Yhi = min(HL-1, (int)ceilf ((h + 1) * inv_scale) + 1);
        const float* xc = x + (size_t)(b*3 + wv) * PL;
        fx4 acc0 = {0.f,0.f,0.f,0.f}, acc1 = {0.f,0.f,0.f,0.f};
        for (int Y = Ylo; Y <= Yhi; ++Y) {
            float fs = Y * scale;
            int i0 = (int)fs; if (i0 > HS-1) i0 = HS-1;
            float f = fs - (float)i0;
            int i1 = min(i0 + 1, HS-1);
            float wt = (i0 == h ? 1.f - f : 0.f) + (i1 == h ? f : 0.f);
            const fx4* xr = (const fx4*)(xc + (size_t)Y * WL);
            acc0 += wt * xr[lane];
            acc1 += wt * xr[lane + 64];
        }
        fx4* t4 = (fx4*)tmp[wv];
        t4[lane]      = acc0;
        t4[lane + 64] = acc1;
        // horizontal (same-wave DS ordering, no barrier needed):
        const int w_ = lane;
        int Xlo = max(0,    (int)floorf((w_ - 1) * inv_scale) - 1);
        int Xhi = min(WL-1, (int)ceilf ((w_ + 1) * inv_scale) + 1);
        float a = 0.f;
        for (int X = Xlo; X <= Xhi; ++X) {
            float fs = X * scale;
            int i0 = (int)fs; if (i0 > WSM-1) i0 = WSM-1;
            float f = fs - (float)i0;
            int i1 = min(i0 + 1, WSM-1);
            float wt = (i0 == w_ ? 1.f - f : 0.f) + (i1 == w_ ? f : 0.f);
            a = fmaf(wt, tmp[wv][X], a);
        }
        sA[wv][lane] = a;
    }

    __syncthreads();                          // sWt ready (and sA ordered)

    // all 4 waves: logits partial over this wave's 64-channel slice
    float part[NK];
    #pragma unroll
    for (int k = 0; k < NK; ++k) part[k] = 0.f;

    const float* fmb = fm + (size_t)b * NC * PS + (size_t)(wv * 64) * PS + p;
    #pragma unroll 8
    for (int cc = 0; cc < 64; ++cc) {
        float v = __builtin_nontemporal_load(fmb + (size_t)cc * PS);
        const float* w = sWt + (wv * 64 + cc) * 22;  // uniform -> LDS broadcast
        #pragma unroll
        for (int k = 0; k < NK; ++k) part[k] = fmaf(v, w[k], part[k]);
    }

    #pragma unroll
    for (int k = 0; k < NK; ++k) red[wv][k][lane] = part[k];
    __syncthreads();

    // every wave reconstructs the full logits (redundant but parallel-free)
    float logit[NK];
    #pragma unroll
    for (int k = 0; k < NK; ++k)
        logit[k] = bc[k] + ((red[0][k][lane] + red[1][k][lane])
                          + (red[2][k][lane] + red[3][k][lane]));

    float m = logit[0];
    #pragma unroll
    for (int k = 1; k < NK; ++k) m = fmaxf(m, logit[k]);
    float s = 0.f;
    #pragma unroll
    for (int k = 0; k < NK; ++k) { logit[k] = __expf(logit[k] - m); s += logit[k]; }
    float inv = 1.f / s;

    float a0 = sA[0][lane], a1 = sA[1][lane], a2 = sA[2][lane];

    // q-partials: wave wv owns k = wv, wv+4, ...; each slot written once.
    float* qb = qpart + (size_t)(b*64 + h) * 64;
    for (int k = wv; k < NK; k += 4) {
        float sv = logit[k] * inv;
        float r0 = sv * a0, r1 = sv * a1, r2 = sv * a2;
        #pragma unroll
        for (int off = 32; off; off >>= 1) {
            r0 += __shfl_down(r0, off);
            r1 += __shfl_down(r1, off);
            r2 += __shfl_down(r2, off);
        }
        if (lane == 0) {
            qb[k*3 + 0] = r0;
            qb[k*3 + 1] = r1;
            qb[k*3 + 2] = r2;
        }
    }
}

// out[b,k,p] = sum_c x[b,c,p] * q[b,k,c]/PL, with q reduced from qpart
// (64 slots/image, L2/L3-resident, coalesced into LDS then summed).
__global__ __launch_bounds__(256) void k_out(
    const float* __restrict__ x, const float* __restrict__ qpart,
    float* __restrict__ out)
{
    __shared__ float lq[64*64];               // 16 KB
    __shared__ float sq[NK*3];
    int tid = threadIdx.x;
    int b = blockIdx.y;

    const fx4* qp4 = (const fx4*)(qpart + (size_t)b * 64 * 64);
    fx4* lq4 = (fx4*)lq;
    #pragma unroll
    for (int j = 0; j < 4; ++j) lq4[tid + j*256] = qp4[tid + j*256];
    __syncthreads();
    if (tid < NK*3) {
        float s = 0.f;
        for (int j = 0; j < 64; ++j) s += lq[j*64 + tid];
        sq[tid] = s * (1.0f / (float)PL);
    }
    __syncthreads();

    int p4 = blockIdx.x * 256 + tid;          // 65536 fx4 per image
    const fx4* xb = (const fx4*)(x + (size_t)b * 3 * PL);
    fx4 x0 = xb[p4];
    fx4 x1 = xb[PL/4 + p4];
    fx4 x2 = xb[2*(PL/4) + p4];
    fx4* ob = (fx4*)(out + (size_t)b * NK * PL);
    #pragma unroll
    for (int k = 0; k < NK; ++k) {
        fx4 o = sq[k*3+0]*x0 + sq[k*3+1]*x1 + sq[k*3+2]*x2;
        __builtin_nontemporal_store(o, ob + (size_t)k * (PL/4) + p4);
    }
}

extern "C" void kernel_launch(void* const* d_in, const int* in_sizes, int n_in,
                              void* d_out, int out_size, void* d_ws, size_t ws_size,
                              hipStream_t stream)
{
    const float* fm = (const float*)d_in[0];   // [8,256,64,64]
    const float* x  = (const float*)d_in[1];   // [8,3,512,512]
    const float* Wc = (const float*)d_in[2];   // [21,256]
    const float* bc = (const float*)d_in[3];   // [21]
    float* out = (float*)d_out;                // [8,21,512,512]

    float* qpart = (float*)d_ws;              // [512][64] floats = 128 KB

    k_fused<<<NB*HS, 256, 0, stream>>>(fm, Wc, bc, x, qpart);
    k_out<<<dim3(PL/4/256, NB), 256, 0, stream>>>(x, qpart, out);
}